// Round 14
// baseline (156.812 us; speedup 1.0000x reference)
//
#include <hip/hip_runtime.h>
#include <math.h>

// -----------------------------------------------------------------------------
// Round 14: lane-per-feature, NO 32-trip transcendental loop anywhere.
// Timeout forensics (rounds 5,6,7,9,12,13 vs successes 3,4,8,10,11): the only
// construct unique to all timeouts is a 32-trip loop over cr_g (f64 log x2)
// through a pointer; round 13 proved noinline+unroll(disable) doesn't defuse
// it. This round removes it structurally:
//  * fast path uses cr_g (exact, CR-f32-via-f64; bit-matched ref on 32M
//    samples in round 3) for the 2 per-feature evals -> margin guard GONE,
//    hot-vs-cold tie resolved exactly (min index).
//  * only remaining hazard: cold top-2 u-gap < 1e-6 (score-plateau; gap
//    >= 1e-6 => score gap >= 2.7e-6 > ulp => exact strict order). Those
//    features (~1e-3 of total) are flagged to a d_ws list (atomicAdd) and
//    fixed by fixup_kernel: 32-lane group per feature, ONE cr_g per lane,
//    butterfly argmax — a clone of round 3's compile-proven kernel shape.
//  * scan and stores are straight-line macro-expanded scalar code: no local
//    arrays, no lambda, no for(;;), no noinline.
// d_ws layout (floats): [0..31] lh, [32..63] lc, [64] coldv, [66] counter
// (int), [67..] flag list (ints, capacity passed from host from ws_size).
// -----------------------------------------------------------------------------

__device__ __forceinline__ float cr_logf32(float x) { return (float)log((double)x); }

__device__ __forceinline__ float cr_g(float u) {
    float c0 = __fadd_rn(u, 1e-30f);
    float t2 = cr_logf32(c0);
    float t3 = __fadd_rn(-t2, 1e-30f);
    float t4 = cr_logf32(t3);
    return -t4;
}

__global__ void traj_kernel(const float* __restrict__ log_x0,
                            const int* __restrict__ t_ptr,
                            float* __restrict__ traj) {
    __shared__ float ac[1001];
    __shared__ float sig[1000];
    __shared__ float init2[2];
    int t = *t_ptr;
    if (t > 1000) t = 1000;
    if (t < 0) t = 0;

    for (int s = threadIdx.x; s <= t; s += blockDim.x) {
        float a = __fdiv_rn((float)s, 1000.0f);
        float b = __fadd_rn(a, 0.008f);
        float c = __fdiv_rn(b, 1.008f);
        float d = __fmul_rn(c, 0x1.921fb6p+1f);  // fl32(pi)
        float e = __fmul_rn(d, 0.5f);
        float cs = (float)cos((double)e);        // CR f32 cos
        ac[s] = __fmul_rn(cs, cs);
    }
    if (threadIdx.x == 0) {
        float hotf = -1e30f, coldf = 1e30f;
        for (int j = 0; j < 32; ++j) {
            float v = log_x0[j];
            hotf = fmaxf(hotf, v);
            coldf = fminf(coldf, v);
        }
        init2[0] = hotf;
        init2[1] = coldf;
        traj[64] = coldf;
        *(int*)(traj + 66) = 0;                  // zero flag counter (each call)
    }
    __syncthreads();
    for (int s = threadIdx.x + 1; s <= t; s += blockDim.x)
        sig[s - 1] = __fsub_rn(1.0f, __fdiv_rn(ac[s], ac[s - 1]));
    __syncthreads();

    if (threadIdx.x < 32) {
        const int h = threadIdx.x;   // hot-bin position (einsum f32 sum order)
        float lh = init2[0];
        float lc = init2[1];
        for (int k = 0; k < t; ++k) {
            float sg = sig[k];
            float ph = (float)exp((double)lh);
            float pc = (float)exp((double)lc);
            float th = __fmul_rn(ph, 0.03125f);
            float tc = __fmul_rn(pc, 0.03125f);
            float acc = 0.0f;
            for (int i = 0; i < 32; ++i)
                acc = __fadd_rn(acc, (i == h) ? th : tc);
            float s1  = __fsub_rn(1.0f, sg);
            float sm  = __fmul_rn(sg, acc);
            float phn = __fadd_rn(__fmul_rn(s1, ph), sm);
            float pcn = __fadd_rn(__fmul_rn(s1, pc), sm);
            lh = cr_logf32(__fadd_rn(phn, 1e-8f));
            lc = cr_logf32(__fadd_rn(pcn, 1e-8f));
        }
        traj[h]      = lh;
        traj[32 + h] = lc;
    }
}

// Branchless scan step for one bin (strict > keeps first index on ties;
// a second equal max pushes t2u == t1u -> plateau flag -> fixup).
#define SCANC(VAL, XVAL, IDX)                                   \
    {                                                           \
        const bool  hx = (XVAL) > -1.0f;                        \
        const float cu = hx ? -1.0f : (VAL);                    \
        hloc = hx ? (IDX) : hloc;                               \
        uhot = hx ? (VAL) : uhot;                               \
        const bool gt1 = cu > t1u;                              \
        const bool gt2 = cu > t2u;                              \
        t2u = gt1 ? t1u : (gt2 ? cu : t2u);                     \
        t1i = gt1 ? (IDX) : t1i;                                \
        t1u = gt1 ? cu : t1u;                                   \
    }

__global__ void sample_kernel(const float4* __restrict__ log_x0,
                              const float4* __restrict__ u,
                              float* __restrict__ trajm,
                              float4* __restrict__ out,
                              int nfeat, int cap) {
    __shared__ float lh_s[32], lc_s[32];
    __shared__ float coldv_s;
    if (threadIdx.x < 32) {
        lh_s[threadIdx.x] = trajm[threadIdx.x];
        lc_s[threadIdx.x] = trajm[32 + threadIdx.x];
    }
    if (threadIdx.x == 0) coldv_s = trajm[64];
    __syncthreads();
    const float coldv = coldv_s;
    int* cnt  = (int*)(trajm + 66);
    int* list = cnt + 1;

    const int f0 = blockIdx.x * blockDim.x + threadIdx.x;
    const int fs = gridDim.x * blockDim.x;

    for (int f = f0; f < nfeat; f += fs) {
        const float4* up = u + (size_t)f * 8;        // 128B/lane
        const float4* xp = log_x0 + (size_t)f * 8;
        const float4 u0 = up[0], u1 = up[1], u2 = up[2], u3 = up[3];
        const float4 u4 = up[4], u5 = up[5], u6 = up[6], u7 = up[7];
        const float4 x0 = xp[0], x1 = xp[1], x2 = xp[2], x3 = xp[3];
        const float4 x4 = xp[4], x5 = xp[5], x6 = xp[6], x7 = xp[7];

        int   hloc = -1;  float uhot = -1.0f;        // hot bin pos + its u
        float t1u  = -1.0f; int t1i = 0;             // cold max-u (first idx)
        float t2u  = -1.0f;                          // cold 2nd max-u

        SCANC(u0.x, x0.x,  0) SCANC(u0.y, x0.y,  1) SCANC(u0.z, x0.z,  2) SCANC(u0.w, x0.w,  3)
        SCANC(u1.x, x1.x,  4) SCANC(u1.y, x1.y,  5) SCANC(u1.z, x1.z,  6) SCANC(u1.w, x1.w,  7)
        SCANC(u2.x, x2.x,  8) SCANC(u2.y, x2.y,  9) SCANC(u2.z, x2.z, 10) SCANC(u2.w, x2.w, 11)
        SCANC(u3.x, x3.x, 12) SCANC(u3.y, x3.y, 13) SCANC(u3.z, x3.z, 14) SCANC(u3.w, x3.w, 15)
        SCANC(u4.x, x4.x, 16) SCANC(u4.y, x4.y, 17) SCANC(u4.z, x4.z, 18) SCANC(u4.w, x4.w, 19)
        SCANC(u5.x, x5.x, 20) SCANC(u5.y, x5.y, 21) SCANC(u5.z, x5.z, 22) SCANC(u5.w, x5.w, 23)
        SCANC(u6.x, x6.x, 24) SCANC(u6.y, x6.y, 25) SCANC(u6.z, x6.z, 26) SCANC(u6.w, x6.w, 27)
        SCANC(u7.x, x7.x, 28) SCANC(u7.y, x7.y, 29) SCANC(u7.z, x7.z, 30) SCANC(u7.w, x7.w, 31)

        const int   h  = (hloc < 0) ? 0 : hloc;
        const float lh = lh_s[h];
        const float lc = lc_s[h];

        // exact hot-vs-cold compare (cr_g is the reference's f32 g bitwise)
        const float s_hot  = __fadd_rn(lh, cr_g(uhot));
        const float s_cold = __fadd_rn(lc, cr_g(t1u));
        int widx;
        if (s_hot > s_cold)      widx = h;
        else if (s_hot < s_cold) widx = t1i;
        else                     widx = (h < t1i) ? h : t1i;  // exact tie

        // plateau / defensive flag -> exact fixup kernel
        if (__builtin_expect(((t1u - t2u) < 1e-6f) | (hloc < 0), 0)) {
            int slot = atomicAdd(cnt, 1);
            if (slot < cap) list[slot] = f;
        }

        float4 o;
        float4* op = out + (size_t)f * 8;
        o.x=(widx== 0)?0.0f:coldv; o.y=(widx== 1)?0.0f:coldv; o.z=(widx== 2)?0.0f:coldv; o.w=(widx== 3)?0.0f:coldv; op[0]=o;
        o.x=(widx== 4)?0.0f:coldv; o.y=(widx== 5)?0.0f:coldv; o.z=(widx== 6)?0.0f:coldv; o.w=(widx== 7)?0.0f:coldv; op[1]=o;
        o.x=(widx== 8)?0.0f:coldv; o.y=(widx== 9)?0.0f:coldv; o.z=(widx==10)?0.0f:coldv; o.w=(widx==11)?0.0f:coldv; op[2]=o;
        o.x=(widx==12)?0.0f:coldv; o.y=(widx==13)?0.0f:coldv; o.z=(widx==14)?0.0f:coldv; o.w=(widx==15)?0.0f:coldv; op[3]=o;
        o.x=(widx==16)?0.0f:coldv; o.y=(widx==17)?0.0f:coldv; o.z=(widx==18)?0.0f:coldv; o.w=(widx==19)?0.0f:coldv; op[4]=o;
        o.x=(widx==20)?0.0f:coldv; o.y=(widx==21)?0.0f:coldv; o.z=(widx==22)?0.0f:coldv; o.w=(widx==23)?0.0f:coldv; op[5]=o;
        o.x=(widx==24)?0.0f:coldv; o.y=(widx==25)?0.0f:coldv; o.z=(widx==26)?0.0f:coldv; o.w=(widx==27)?0.0f:coldv; op[6]=o;
        o.x=(widx==28)?0.0f:coldv; o.y=(widx==29)?0.0f:coldv; o.z=(widx==30)?0.0f:coldv; o.w=(widx==31)?0.0f:coldv; op[7]=o;
    }
}

// Exact per-bin argmax for flagged features: clone of round 3's compile-proven
// shape — 32-lane group per feature, ONE cr_g per lane, butterfly argmax.
__global__ void fixup_kernel(const float* __restrict__ log_x0,
                             const float* __restrict__ u,
                             float* __restrict__ trajm,
                             float* __restrict__ out,
                             int cap) {
    __shared__ float lh_s[32], lc_s[32];
    __shared__ float coldv_s;
    if (threadIdx.x < 32) {
        lh_s[threadIdx.x] = trajm[threadIdx.x];
        lc_s[threadIdx.x] = trajm[32 + threadIdx.x];
    }
    if (threadIdx.x == 0) coldv_s = trajm[64];
    __syncthreads();
    const float coldv = coldv_s;
    const int* cnt  = (const int*)(trajm + 66);
    const int* list = cnt + 1;

    int n = *cnt;
    if (n > cap) n = cap;

    const int lane32  = threadIdx.x & 31;
    const int group   = (int)((blockIdx.x * blockDim.x + threadIdx.x) >> 5);
    const int ngroups = (int)((gridDim.x * blockDim.x) >> 5);
    const int shift   = (threadIdx.x & 32) ? 32 : 0;

    for (int i = group; i < n; i += ngroups) {
        const int f = list[i];
        const int base = f * 32 + lane32;
        const float uf = u[base];
        const float xf = log_x0[base];
        const bool hot = xf > -1.0f;

        unsigned long long bal = __ballot(hot);
        unsigned mm = (unsigned)(bal >> shift);
        int h = mm ? (__ffs(mm) - 1) : 0;

        float L = hot ? lh_s[h] : lc_s[h];
        float s = __fadd_rn(L, cr_g(uf));

        int idx = lane32;
        #pragma unroll
        for (int m = 16; m > 0; m >>= 1) {
            float os = __shfl_xor(s,   m, 32);
            int   oi = __shfl_xor(idx, m, 32);
            if (os > s || (os == s && oi < idx)) {
                s = os;
                idx = oi;
            }
        }
        out[base] = (lane32 == idx) ? 0.0f : coldv;
    }
}

extern "C" void kernel_launch(void* const* d_in, const int* in_sizes, int n_in,
                              void* d_out, int out_size, void* d_ws, size_t ws_size,
                              hipStream_t stream) {
    const float* log_x0 = (const float*)d_in[0];
    const float* u      = (const float*)d_in[1];
    const int*   t_ptr  = (const int*)d_in[2];
    float* out  = (float*)d_out;
    float* traj = (float*)d_ws;

    const int nfeat = in_sizes[0] / 32;   // B*F = 1,048,576

    long long avail = (long long)(ws_size / 4) - 80;
    int cap = (avail < 0) ? 0 : ((avail > 16384) ? 16384 : (int)avail);

    traj_kernel<<<1, 128, 0, stream>>>(log_x0, t_ptr, traj);

    sample_kernel<<<2048, 256, 0, stream>>>((const float4*)log_x0,
                                            (const float4*)u, traj,
                                            (float4*)out, nfeat, cap);

    fixup_kernel<<<256, 256, 0, stream>>>(log_x0, u, traj, out, cap);
}

// Round 15
// 137.036 us; speedup vs baseline: 1.1443x; 1.1443x over previous
//
#include <hip/hip_runtime.h>
#include <math.h>

// -----------------------------------------------------------------------------
// Round 15: wave-local LDS transpose. Round 14 proved lane-per-feature compute
// is cheap (VALUBusy 14%) but its 128B-strided access is transaction-bound
// (~24 line-txns/feature ~= the whole 130us). Fix: coalesced global access in
// BOTH directions + LDS redistribution, all within one wave (no cross-wave
// sync; one uniform __syncthreads per tile).
//   stage:  8 coalesced float4 u-loads -> stride-33 LDS scatter (bank
//           (g+4q+c)%32: conflict-free); x folded to 1 hot-byte/feature via
//           8-lane ballot (x never staged).
//   read:   lane==feature: 32 rotated b32 LDS reads (bank (lane+j)%32),
//           branchless top-2 cold scan, 2 exact cr_g (round-14-proven, no
//           margin guard), plateau/defensive -> flag list + fixup kernel
//           (round 14's, compile-proven).
//   store:  all-cold float4s coalesced, winner patched in-flight via one
//           __shfl per step (single store per address).
// d_ws: [0..31] lh, [32..63] lc, [64] coldv, [66] int counter, [67..] flags.
// -----------------------------------------------------------------------------

__device__ __forceinline__ float cr_logf32(float x) { return (float)log((double)x); }

__device__ __forceinline__ float cr_g(float u) {
    float c0 = __fadd_rn(u, 1e-30f);
    float t2 = cr_logf32(c0);
    float t3 = __fadd_rn(-t2, 1e-30f);
    float t4 = cr_logf32(t3);
    return -t4;
}

__global__ void traj_kernel(const float* __restrict__ log_x0,
                            const int* __restrict__ t_ptr,
                            float* __restrict__ traj) {
    __shared__ float ac[1001];
    __shared__ float sig[1000];
    __shared__ float init2[2];
    int t = *t_ptr;
    if (t > 1000) t = 1000;
    if (t < 0) t = 0;

    for (int s = threadIdx.x; s <= t; s += blockDim.x) {
        float a = __fdiv_rn((float)s, 1000.0f);
        float b = __fadd_rn(a, 0.008f);
        float c = __fdiv_rn(b, 1.008f);
        float d = __fmul_rn(c, 0x1.921fb6p+1f);  // fl32(pi)
        float e = __fmul_rn(d, 0.5f);
        float cs = (float)cos((double)e);        // CR f32 cos
        ac[s] = __fmul_rn(cs, cs);
    }
    if (threadIdx.x == 0) {
        float hotf = -1e30f, coldf = 1e30f;
        for (int j = 0; j < 32; ++j) {
            float v = log_x0[j];
            hotf = fmaxf(hotf, v);
            coldf = fminf(coldf, v);
        }
        init2[0] = hotf;
        init2[1] = coldf;
        traj[64] = coldf;
        *(int*)(traj + 66) = 0;                  // zero flag counter (each call)
    }
    __syncthreads();
    for (int s = threadIdx.x + 1; s <= t; s += blockDim.x)
        sig[s - 1] = __fsub_rn(1.0f, __fdiv_rn(ac[s], ac[s - 1]));
    __syncthreads();

    if (threadIdx.x < 32) {
        const int h = threadIdx.x;   // hot-bin position (einsum f32 sum order)
        float lh = init2[0];
        float lc = init2[1];
        for (int k = 0; k < t; ++k) {
            float sg = sig[k];
            float ph = (float)exp((double)lh);
            float pc = (float)exp((double)lc);
            float th = __fmul_rn(ph, 0.03125f);
            float tc = __fmul_rn(pc, 0.03125f);
            float acc = 0.0f;
            for (int i = 0; i < 32; ++i)
                acc = __fadd_rn(acc, (i == h) ? th : tc);
            float s1  = __fsub_rn(1.0f, sg);
            float sm  = __fmul_rn(sg, acc);
            float phn = __fadd_rn(__fmul_rn(s1, ph), sm);
            float pcn = __fadd_rn(__fmul_rn(s1, pc), sm);
            lh = cr_logf32(__fadd_rn(phn, 1e-8f));
            lc = cr_logf32(__fadd_rn(pcn, 1e-8f));
        }
        traj[h]      = lh;
        traj[32 + h] = lc;
    }
}

__global__ void sample_kernel(const float4* __restrict__ log_x0,
                              const float4* __restrict__ u,
                              float* __restrict__ trajm,
                              float4* __restrict__ out,
                              int ntile, int cap) {
    __shared__ float lds_u[4][2112];             // 64 feat x 33 floats, per wave
    __shared__ unsigned char lds_h[4][64];       // hot bin per feature
    __shared__ float lh_s[32], lc_s[32];
    __shared__ float coldv_s;
    if (threadIdx.x < 32) {
        lh_s[threadIdx.x] = trajm[threadIdx.x];
        lc_s[threadIdx.x] = trajm[32 + threadIdx.x];
    }
    if (threadIdx.x == 0) coldv_s = trajm[64];
    __syncthreads();
    const float coldv = coldv_s;
    int* cnt  = (int*)(trajm + 66);
    int* list = cnt + 1;

    const int w     = threadIdx.x >> 6;          // wave in block (0..3)
    const int lane  = threadIdx.x & 63;
    const int wid   = (int)((blockIdx.x * blockDim.x + threadIdx.x) >> 6);
    const int nwav  = (int)((gridDim.x * blockDim.x) >> 6);

    for (int tile = wid; tile < ntile; tile += nwav) {
        const size_t fb8 = (size_t)tile * 512;   // flat float4 base (64 feat * 8)

        // ---- stage u: coalesced loads -> stride-33 conflict-free scatter ----
        #pragma unroll
        for (int k = 0; k < 8; ++k) {
            const float4 v = u[fb8 + k * 64 + lane];
            const int lj = k * 64 + lane;        // local float4 idx
            const int fl = lj >> 3;              // local feature
            const int q  = lj & 7;               // quarter
            float* dst = &lds_u[w][fl * 33 + q * 4];
            dst[0] = v.x; dst[1] = v.y; dst[2] = v.z; dst[3] = v.w;
        }
        // ---- stage x: ballot per 8-lane subgroup -> hot byte per feature ----
        #pragma unroll
        for (int k = 0; k < 8; ++k) {
            const float4 xv = log_x0[fb8 + k * 64 + lane];
            int p = -1;
            p = (xv.x > -1.0f) ? 0 : p;
            p = (xv.y > -1.0f) ? 1 : p;
            p = (xv.z > -1.0f) ? 2 : p;
            p = (xv.w > -1.0f) ? 3 : p;
            const unsigned long long bal = __ballot(p >= 0);
            const int sgb = lane & ~7;           // subgroup base lane
            const unsigned mm = (unsigned)((bal >> sgb) & 0xFFull);
            const int hlane = (int)__ffs(mm) - 1;            // 0..7 or -1
            const int psrc  = __shfl(p, sgb + ((hlane < 0) ? 0 : hlane), 64);
            const int hbin  = (hlane < 0) ? 255 : (hlane * 4 + psrc);
            if ((lane & 7) == 0)
                lds_h[w][k * 8 + (lane >> 3)] = (unsigned char)hbin;
        }
        __syncthreads();                         // uniform (exact tile counts)

        // ---- per-lane: own one feature ----
        const int   h  = (int)lds_h[w][lane];
        const int   hc = (h > 31) ? 0 : h;
        const float lh = lh_s[hc];
        const float lc = lc_s[hc];
        const float* urow = &lds_u[w][lane * 33];  // bank rotation (lane+j)%32

        float t1u = -1.0f, t2u = -1.0f; int t1i = 0;
        #pragma unroll
        for (int j = 0; j < 32; ++j) {
            const float cu = (j == hc) ? -1.0f : urow[j];
            const bool gt1 = cu > t1u;
            const bool gt2 = cu > t2u;
            t2u = gt1 ? t1u : (gt2 ? cu : t2u);
            t1i = gt1 ? j : t1i;
            t1u = gt1 ? cu : t1u;
        }
        const float uhot = urow[hc];

        const float s_hot  = __fadd_rn(lh, cr_g(uhot));
        const float s_cold = __fadd_rn(lc, cr_g(t1u));
        int widx;
        if (s_hot > s_cold)      widx = hc;
        else if (s_hot < s_cold) widx = t1i;
        else                     widx = (hc < t1i) ? hc : t1i;  // exact tie

        if (__builtin_expect(((t1u - t2u) < 1e-6f) | (h > 31), 0)) {
            int slot = atomicAdd(cnt, 1);
            if (slot < cap) list[slot] = tile * 64 + lane;
        }

        // ---- store: coalesced all-cold, winner patched via shfl ----
        #pragma unroll
        for (int k = 0; k < 8; ++k) {
            const int src = k * 8 + (lane >> 3);         // owner lane of this float4's feature
            const int wk  = __shfl(widx, src, 64);
            const int qb  = (lane & 7) * 4;              // bins covered: qb..qb+3
            float4 o;
            o.x = (wk == qb    ) ? 0.0f : coldv;
            o.y = (wk == qb + 1) ? 0.0f : coldv;
            o.z = (wk == qb + 2) ? 0.0f : coldv;
            o.w = (wk == qb + 3) ? 0.0f : coldv;
            out[fb8 + k * 64 + lane] = o;
        }
        __syncthreads();                         // protect lds before next stage
    }
}

// Exact per-bin argmax for flagged features (round 14, compile-proven).
__global__ void fixup_kernel(const float* __restrict__ log_x0,
                             const float* __restrict__ u,
                             float* __restrict__ trajm,
                             float* __restrict__ out,
                             int cap) {
    __shared__ float lh_s[32], lc_s[32];
    __shared__ float coldv_s;
    if (threadIdx.x < 32) {
        lh_s[threadIdx.x] = trajm[threadIdx.x];
        lc_s[threadIdx.x] = trajm[32 + threadIdx.x];
    }
    if (threadIdx.x == 0) coldv_s = trajm[64];
    __syncthreads();
    const float coldv = coldv_s;
    const int* cnt  = (const int*)(trajm + 66);
    const int* list = cnt + 1;

    int n = *cnt;
    if (n > cap) n = cap;

    const int lane32  = threadIdx.x & 31;
    const int group   = (int)((blockIdx.x * blockDim.x + threadIdx.x) >> 5);
    const int ngroups = (int)((gridDim.x * blockDim.x) >> 5);
    const int shift   = (threadIdx.x & 32) ? 32 : 0;

    for (int i = group; i < n; i += ngroups) {
        const int f = list[i];
        const int base = f * 32 + lane32;
        const float uf = u[base];
        const float xf = log_x0[base];
        const bool hot = xf > -1.0f;

        unsigned long long bal = __ballot(hot);
        unsigned mm = (unsigned)(bal >> shift);
        int h = mm ? (__ffs(mm) - 1) : 0;

        float L = hot ? lh_s[h] : lc_s[h];
        float s = __fadd_rn(L, cr_g(uf));

        int idx = lane32;
        #pragma unroll
        for (int m = 16; m > 0; m >>= 1) {
            float os = __shfl_xor(s,   m, 32);
            int   oi = __shfl_xor(idx, m, 32);
            if (os > s || (os == s && oi < idx)) {
                s = os;
                idx = oi;
            }
        }
        out[base] = (lane32 == idx) ? 0.0f : coldv;
    }
}

extern "C" void kernel_launch(void* const* d_in, const int* in_sizes, int n_in,
                              void* d_out, int out_size, void* d_ws, size_t ws_size,
                              hipStream_t stream) {
    const float* log_x0 = (const float*)d_in[0];
    const float* u      = (const float*)d_in[1];
    const int*   t_ptr  = (const int*)d_in[2];
    float* out  = (float*)d_out;
    float* traj = (float*)d_ws;

    const int nfeat = in_sizes[0] / 32;   // B*F = 1,048,576
    const int ntile = nfeat / 64;         // 16384 (exact)

    long long avail = (long long)(ws_size / 4) - 80;
    int cap = (avail < 0) ? 0 : ((avail > 16384) ? 16384 : (int)avail);

    traj_kernel<<<1, 128, 0, stream>>>(log_x0, t_ptr, traj);

    sample_kernel<<<2048, 256, 0, stream>>>((const float4*)log_x0,
                                            (const float4*)u, traj,
                                            (float4*)out, ntile, cap);

    fixup_kernel<<<256, 256, 0, stream>>>(log_x0, u, traj, out, cap);
}